// Round 14
// baseline (319.342 us; speedup 1.0000x reference)
//
#include <hip/hip_runtime.h>
#include <hip/hip_cooperative_groups.h>

namespace cg = cooperative_groups;

#define TWO_PI_F 6.283185307179586f

__device__ __forceinline__ float clamp02pi(float x) {
    return fminf(fmaxf(x, 0.0f), TWO_PI_F);
}

__device__ __forceinline__ float2 cmul(const float2 a, const float2 b) {
    return make_float2(a.x * b.x - a.y * b.y, a.x * b.y + a.y * b.x);
}
__device__ __forceinline__ float2 cadd(const float2 a, const float2 b) {
    return make_float2(a.x + b.x, a.y + b.y);
}
__device__ __forceinline__ float2 cscale(const float s, const float2 a) {
    return make_float2(s * a.x, s * a.y);
}
__device__ __forceinline__ float2 imul(const float r, const float2 e) {  // i*r*e
    return make_float2(-r * e.y, r * e.x);
}

// Banded row apply: out = c0.xy*a + c0.zw*b + c1.xy*d + c1.zw*e (complex).
__device__ __forceinline__ float2 row4(const float4 c0, const float4 c1,
                                       const float2 a, const float2 b,
                                       const float2 d, const float2 e)
{
    float re = c0.x * a.x - c0.y * a.y;
    float im = c0.x * a.y + c0.y * a.x;
    re += c0.z * b.x - c0.w * b.y;  im += c0.z * b.y + c0.w * b.x;
    re += c1.x * d.x - c1.y * d.y;  im += c1.x * d.y + c1.y * d.x;
    re += c1.z * e.x - c1.w * e.y;  im += c1.z * e.y + c1.w * e.x;
    return make_float2(re, im);
}

// ---------------------------------------------------------------------------
// Composition of row r for step i (math verbatim R12/R13 — verified, absmax
// 3.7e-9). Layer coefs for the step's 4 sub-layers come from LDS (sE/sO).
// Row r's band = 4 complex coefs over input rows base..base+3,
// base = (r even) ? r-2 : r-1. Out: h0 = (f0,f1), h1 = (f2,f3).
// Row 0: f0,f1 = 0 (cols -2,-1). Row 511: f2,f3 = 0 (cols 512,513).
// ---------------------------------------------------------------------------
__device__ __forceinline__ void compose_row(
    const float4 (*sE)[256], const float4 (*sO)[256], const int r,
    float4& h0, float4& h1)
{
    float2 f0, f1, f2, f3;
    if (r == 0) {
        const float4 q1 = sE[1][0], q0 = sE[0][0];
        const float2 e1 = make_float2(q1.x, q1.y);
        const float2 e0 = make_float2(q0.x, q0.y);
        const float2 v2 = cscale(q1.z, e1);
        const float2 v3 = make_float2(0.0f, q1.w);
        f2 = cadd(cmul(v2, cscale(q0.z, e0)), cmul(v3, imul(q0.w, e0)));
        f3 = cadd(cmul(v2, make_float2(0.0f, q0.w)), cscale(q0.z, v3));
        f0 = make_float2(0.0f, 0.0f);
        f1 = make_float2(0.0f, 0.0f);
    } else {
        const int pidx = (r - 1) >> 1;
        const int qidx = min(pidx + 1, 255);      // r=511: u2==0, value unused
        const float4 qO1 = sO[1][pidx], qO0 = sO[0][pidx];
        const float2 eO1 = make_float2(qO1.x, qO1.y);
        const float2 eO0 = make_float2(qO0.x, qO0.y);
        float2 w1, w2;
        if (r & 1) { w1 = cscale(qO1.z, eO1); w2 = make_float2(0.0f, qO1.w); }
        else       { w1 = imul(qO1.w, eO1);   w2 = make_float2(qO1.z, 0.0f); }
        const float2 u1 = cadd(cmul(w1, cscale(qO0.z, eO0)),
                               cmul(w2, imul(qO0.w, eO0)));
        const float2 u2 = cadd(cmul(w1, make_float2(0.0f, qO0.w)),
                               cscale(qO0.z, w2));
        const float4 qE1p = sE[1][pidx], qE1q = sE[1][qidx];
        const float4 qE0p = sE[0][pidx], qE0q = sE[0][qidx];
        const float2 eE1p = make_float2(qE1p.x, qE1p.y);
        const float2 eE1q = make_float2(qE1q.x, qE1q.y);
        const float2 eE0p = make_float2(qE0p.x, qE0p.y);
        const float2 eE0q = make_float2(qE0q.x, qE0q.y);
        const float2 v0 = cmul(u1, imul(qE1p.w, eE1p));
        const float2 v1 = cscale(qE1p.z, u1);
        const float2 v2 = cmul(u2, cscale(qE1q.z, eE1q));
        const float2 v3 = cmul(u2, make_float2(0.0f, qE1q.w));
        f0 = cadd(cmul(v0, cscale(qE0p.z, eE0p)), cmul(v1, imul(qE0p.w, eE0p)));
        f1 = cadd(cmul(v0, make_float2(0.0f, qE0p.w)), cscale(qE0p.z, v1));
        f2 = cadd(cmul(v2, cscale(qE0q.z, eE0q)), cmul(v3, imul(qE0q.w, eE0q)));
        f3 = cadd(cmul(v2, make_float2(0.0f, qE0q.w)), cscale(qE0q.z, v3));
    }
    h0 = make_float4(f0.x, f0.y, f1.x, f1.y);
    h1 = make_float4(f2.x, f2.y, f3.x, f3.y);
}

// Stage the 4 sub-layer coef sets of step i into LDS (512 threads, 2 each).
__device__ __forceinline__ void stage_layer_coefs(
    const float* __restrict__ pe, const float* __restrict__ po,
    const float* __restrict__ le, const float* __restrict__ ie,
    const float* __restrict__ lo, const float* __restrict__ io,
    const int i, const int t, float4 (*sE)[256], float4 (*sO)[256])
{
    {
        const int sub = t >> 8, pp = t & 255;
        const int idx = (2 * i + sub) * 256 + pp;
        float s, c;
        __sincosf(clamp02pi(pe[idx]), &s, &c);
        const float a = sqrtf(1.0f - le[idx]);
        sE[sub][pp] = make_float4(c, s, a * sqrtf(0.5f + ie[idx]),
                                        a * sqrtf(0.5f - ie[idx]));
    }
    {
        const int sub = t >> 8, pp = t & 255;
        float4 q = make_float4(1.0f, 0.0f, 1.0f, 0.0f);
        if (pp < 255) {
            const int odx = (2 * i + sub) * 255 + pp;
            float s, c;
            __sincosf(clamp02pi(po[odx]), &s, &c);
            const float a = sqrtf(1.0f - lo[odx]);
            q = make_float4(c, s, a * sqrtf(0.5f + io[odx]),
                                  a * sqrtf(0.5f - io[odx]));
        }
        sO[sub][pp] = q;
    }
}

// ---------------------------------------------------------------------------
// FUSED cooperative kernel. Grid 512 x 512, LDS padded to ~53.5 KB so exactly
// 2 blocks/CU are co-resident (16 waves/CU) and grid == capacity.
// Phase 1: blocks 0..255 compose step g into Mc (layout: Mc[i*1024 + r] = h0,
//          Mc[i*1024 + 512 + r] = h1) — coalesced row-major per step.
// grid.sync()
// Phase 2: block g = column g; thread r owns row r. State = double-buffered
//          padded LDS rows (S index = 2 + row; pads are zero and hit
//          exactly-zero band coefs). Per step: 2 coalesced float4 coef loads
//          (prefetched), 2x ds_read_b128 (read base rb even -> 16B aligned),
//          16 FMA, 1 ds_write_b64, one barrier.
// ---------------------------------------------------------------------------
__global__ __launch_bounds__(512, 1) void fused_kernel(
    const float* __restrict__ pe, const float* __restrict__ po,
    const float* __restrict__ pout,
    const float* __restrict__ le, const float* __restrict__ ie,
    const float* __restrict__ lo, const float* __restrict__ io,
    float4* __restrict__ Mc, float* __restrict__ out, const int out_size)
{
    __shared__ float4 sE[2][256];      // 8 KB
    __shared__ float4 sO[2][256];      // 8 KB
    __shared__ float2 S[2][2400];      // 37.5 KB; [0..515] used, rest = pad to
                                       // force <=2 blocks/CU (total ~53.5 KB)

    const int t = threadIdx.x;   // 0..511
    const int g = blockIdx.x;    // 0..511

    // ---- Phase 1: compose (blocks 0..255; one step per block) ----
    if (g < 256) {
        stage_layer_coefs(pe, po, le, ie, lo, io, g, t, sE, sO);
        __syncthreads();
        float4 h0, h1;
        compose_row(sE, sO, t, h0, h1);
        Mc[g * 1024 + t]       = h0;
        Mc[g * 1024 + 512 + t] = h1;
    }
    __threadfence();
    cg::this_grid().sync();

    // ---- Phase 2: mesh scan; block g = column ----
    const int col = g;
    const int r = t;
    if (t < 2) {  // zero pads of both buffers (never written afterwards)
        S[0][t] = make_float2(0.0f, 0.0f);
        S[1][t] = make_float2(0.0f, 0.0f);
        S[0][514 + t] = make_float2(0.0f, 0.0f);
        S[1][514 + t] = make_float2(0.0f, 0.0f);
    }
    S[0][2 + r] = make_float2((r == col) ? 1.0f : 0.0f, 0.0f);

    // read base: S index rb..rb+3 = input rows base..base+3 (+2 offset);
    // even r -> rb = r, odd r -> rb = r+1; rb always even -> 16B-aligned.
    const int rb = (r & 1) ? (r + 1) : r;
    float4 c0 = Mc[r], c1 = Mc[512 + r];
    float2 Y = make_float2(0.0f, 0.0f);
    __syncthreads();

#pragma unroll 1
    for (int i = 0; i < 256; ++i) {
        const int nb = ((i + 1) & 255) * 1024 + r;     // prefetch (wrap ok)
        const float4 n0 = Mc[nb], n1 = Mc[nb + 512];

        const float2* Sc = S[i & 1];
        const float2 a = Sc[rb], b = Sc[rb + 1], d = Sc[rb + 2], e = Sc[rb + 3];
        Y = row4(c0, c1, a, b, d, e);
        S[(i + 1) & 1][2 + r] = Y;
        __syncthreads();

        c0 = n0; c1 = n1;
    }

    // ---- output phase; expected output = Re(M), row-major, guarded ----
    float s, c;
    __sincosf(clamp02pi(pout[r]), &s, &c);
    const int o = r * 512 + col;
    if (o < out_size) out[o] = c * Y.x - s * Y.y;
}

// ---------------------------------------------------------------------------
// Fallback pair (same math, plain launches) — used if cooperative launch
// is rejected by the runtime/graph capture.
// ---------------------------------------------------------------------------
__global__ __launch_bounds__(512) void compose_kernel(
    const float* __restrict__ pe, const float* __restrict__ po,
    const float* __restrict__ le, const float* __restrict__ ie,
    const float* __restrict__ lo, const float* __restrict__ io,
    float4* __restrict__ Mc)
{
    __shared__ float4 sE[2][256];
    __shared__ float4 sO[2][256];
    const int i = blockIdx.x;    // step
    const int t = threadIdx.x;   // row
    stage_layer_coefs(pe, po, le, ie, lo, io, i, t, sE, sO);
    __syncthreads();
    float4 h0, h1;
    compose_row(sE, sO, t, h0, h1);
    Mc[i * 1024 + t]       = h0;
    Mc[i * 1024 + 512 + t] = h1;
}

__global__ __launch_bounds__(512) void mesh_row_kernel(
    const float4* __restrict__ Mc,
    const float* __restrict__ pout,
    float* __restrict__ out, const int out_size)
{
    __shared__ float2 S[2][516];
    const int r   = threadIdx.x;
    const int col = blockIdx.x;

    if (r < 2) {
        S[0][r] = make_float2(0.0f, 0.0f);
        S[1][r] = make_float2(0.0f, 0.0f);
        S[0][514 + r] = make_float2(0.0f, 0.0f);
        S[1][514 + r] = make_float2(0.0f, 0.0f);
    }
    S[0][2 + r] = make_float2((r == col) ? 1.0f : 0.0f, 0.0f);

    const int rb = (r & 1) ? (r + 1) : r;
    float4 c0 = Mc[r], c1 = Mc[512 + r];
    float2 Y = make_float2(0.0f, 0.0f);
    __syncthreads();

#pragma unroll 1
    for (int i = 0; i < 256; ++i) {
        const int nb = ((i + 1) & 255) * 1024 + r;
        const float4 n0 = Mc[nb], n1 = Mc[nb + 512];
        const float2* Sc = S[i & 1];
        const float2 a = Sc[rb], b = Sc[rb + 1], d = Sc[rb + 2], e = Sc[rb + 3];
        Y = row4(c0, c1, a, b, d, e);
        S[(i + 1) & 1][2 + r] = Y;
        __syncthreads();
        c0 = n0; c1 = n1;
    }

    float s, c;
    __sincosf(clamp02pi(pout[r]), &s, &c);
    const int o = r * 512 + col;
    if (o < out_size) out[o] = c * Y.x - s * Y.y;
}

extern "C" void kernel_launch(void* const* d_in, const int* in_sizes, int n_in,
                              void* d_out, int out_size, void* d_ws, size_t ws_size,
                              hipStream_t stream)
{
    const float* pe   = (const float*)d_in[0];  // pc_even_phases  [512][256]
    const float* po   = (const float*)d_in[1];  // pc_odd_phases   [512][255]
    const float* pout = (const float*)d_in[2];  // pc_out_phases   [512]
    const float* le   = (const float*)d_in[3];  // mmi_loss_even   [512][256]
    const float* ie   = (const float*)d_in[4];  // mmi_imb_even    [512][256]
    const float* lo   = (const float*)d_in[5];  // mmi_loss_odd    [512][255]
    const float* io   = (const float*)d_in[6];  // mmi_imb_odd     [512][255]
    float4* Mc  = (float4*)d_ws;                // 256*1024 float4 = 4 MB
    float* outp = (float*)d_out;
    int osz = out_size;

    void* args[] = { (void*)&pe, (void*)&po, (void*)&pout, (void*)&le,
                     (void*)&ie, (void*)&lo, (void*)&io, (void*)&Mc,
                     (void*)&outp, (void*)&osz };
    hipError_t err = hipLaunchCooperativeKernel(
        (const void*)fused_kernel, dim3(512), dim3(512), args, 0, stream);
    if (err != hipSuccess) {
        // fallback: same math as two plain launches
        compose_kernel<<<256, 512, 0, stream>>>(pe, po, le, ie, lo, io, Mc);
        mesh_row_kernel<<<512, 512, 0, stream>>>(Mc, pout, outp, osz);
    }
}

// Round 15
// 150.277 us; speedup vs baseline: 2.1250x; 2.1250x over previous
//
#include <hip/hip_runtime.h>

#define TWO_PI_F 6.283185307179586f

__device__ __forceinline__ float clamp02pi(float x) {
    return fminf(fmaxf(x, 0.0f), TWO_PI_F);
}

__device__ __forceinline__ float2 cmul(const float2 a, const float2 b) {
    return make_float2(a.x * b.x - a.y * b.y, a.x * b.y + a.y * b.x);
}
__device__ __forceinline__ float2 cadd(const float2 a, const float2 b) {
    return make_float2(a.x + b.x, a.y + b.y);
}
__device__ __forceinline__ float2 cscale(const float s, const float2 a) {
    return make_float2(s * a.x, s * a.y);
}
__device__ __forceinline__ float2 imul(const float r, const float2 e) {  // i*r*e
    return make_float2(-r * e.y, r * e.x);
}
__device__ __forceinline__ float2 cfma(const float2 acc, const float2 a, const float2 b) {
    return make_float2(acc.x + a.x * b.x - a.y * b.y,
                       acc.y + a.x * b.y + a.y * b.x);
}

// Band-4 composition of row r for one 4-layer step (math verbatim R12-R14 —
// verified, absmax 3.7e-9). h0 = cols base..base+1, h1 = cols base+2..base+3,
// base = r even ? r-2 : r-1. Row 0: h0 = 0. Row 511: h1 = 0.
__device__ __forceinline__ void compose_row(
    const float4 (*sE)[256], const float4 (*sO)[256], const int r,
    float4& h0, float4& h1)
{
    float2 f0, f1, f2, f3;
    if (r == 0) {
        const float4 q1 = sE[1][0], q0 = sE[0][0];
        const float2 e1 = make_float2(q1.x, q1.y);
        const float2 e0 = make_float2(q0.x, q0.y);
        const float2 v2 = cscale(q1.z, e1);
        const float2 v3 = make_float2(0.0f, q1.w);
        f2 = cadd(cmul(v2, cscale(q0.z, e0)), cmul(v3, imul(q0.w, e0)));
        f3 = cadd(cmul(v2, make_float2(0.0f, q0.w)), cscale(q0.z, v3));
        f0 = make_float2(0.0f, 0.0f);
        f1 = make_float2(0.0f, 0.0f);
    } else {
        const int pidx = (r - 1) >> 1;
        const int qidx = min(pidx + 1, 255);      // r=511: u2==0, value unused
        const float4 qO1 = sO[1][pidx], qO0 = sO[0][pidx];
        const float2 eO1 = make_float2(qO1.x, qO1.y);
        const float2 eO0 = make_float2(qO0.x, qO0.y);
        float2 w1, w2;
        if (r & 1) { w1 = cscale(qO1.z, eO1); w2 = make_float2(0.0f, qO1.w); }
        else       { w1 = imul(qO1.w, eO1);   w2 = make_float2(qO1.z, 0.0f); }
        const float2 u1 = cadd(cmul(w1, cscale(qO0.z, eO0)),
                               cmul(w2, imul(qO0.w, eO0)));
        const float2 u2 = cadd(cmul(w1, make_float2(0.0f, qO0.w)),
                               cscale(qO0.z, w2));
        const float4 qE1p = sE[1][pidx], qE1q = sE[1][qidx];
        const float4 qE0p = sE[0][pidx], qE0q = sE[0][qidx];
        const float2 eE1p = make_float2(qE1p.x, qE1p.y);
        const float2 eE1q = make_float2(qE1q.x, qE1q.y);
        const float2 eE0p = make_float2(qE0p.x, qE0p.y);
        const float2 eE0q = make_float2(qE0q.x, qE0q.y);
        const float2 v0 = cmul(u1, imul(qE1p.w, eE1p));
        const float2 v1 = cscale(qE1p.z, u1);
        const float2 v2 = cmul(u2, cscale(qE1q.z, eE1q));
        const float2 v3 = cmul(u2, make_float2(0.0f, qE1q.w));
        f0 = cadd(cmul(v0, cscale(qE0p.z, eE0p)), cmul(v1, imul(qE0p.w, eE0p)));
        f1 = cadd(cmul(v0, make_float2(0.0f, qE0p.w)), cscale(qE0p.z, v1));
        f2 = cadd(cmul(v2, cscale(qE0q.z, eE0q)), cmul(v3, imul(qE0q.w, eE0q)));
        f3 = cadd(cmul(v2, make_float2(0.0f, qE0q.w)), cscale(qE0q.z, v3));
    }
    h0 = make_float4(f0.x, f0.y, f1.x, f1.y);
    h1 = make_float4(f2.x, f2.y, f3.x, f3.y);
}

// ---------------------------------------------------------------------------
// Kernel 1: fused 2-level composition. Block j = superstep (layers 4j..4j+3).
// Phase A: stage layer coefs (4 sub-layers x 256 pairs) into LDS.
// Phase B: band-4 rows for both child steps into LDS (verified compose_row).
// Phase C: band-8 product P = S2*S1. Row r: base = r even ? r-2 : r-1;
//   w_m = S2[r, base+m]; P[off_m + n] += w_m * S1[base+m, n-th band col],
//   off = {0,2,2,4} (derived from the parity of base+m — uniform for both
//   parities of r). k clamped to [0,511]; OOB only for rows 0/511 where the
//   corresponding w_m is exactly 0, so clamped reads never contaminate.
//   All out-of-window entries of P are exact zeros -> mesh pad trick valid.
// Output: Mc8[j*2048 + h*256 + t], h=0..3 -> row 2t's 4 float4 (8 complex,
// window base 2t-4), h=4..7 -> row 2t+1's (window base 2t-2).
// ---------------------------------------------------------------------------
__global__ __launch_bounds__(512) void compose8_kernel(
    const float* __restrict__ pe, const float* __restrict__ po,
    const float* __restrict__ le, const float* __restrict__ ie,
    const float* __restrict__ lo, const float* __restrict__ io,
    float4* __restrict__ Mc8)
{
    const int j = blockIdx.x;    // superstep 0..127
    const int t = threadIdx.x;   // 0..511

    __shared__ float4 sE[4][256];      // 16 KB
    __shared__ float4 sO[4][256];      // 16 KB
    __shared__ float4 B4[2][512][2];   // 32 KB: [step][row][h]

    // ---- Phase A: stage (each thread: 2 E + 2 O pair-coefs) ----
#pragma unroll
    for (int q = 0; q < 2; ++q) {
        const int item = q * 512 + t;      // 0..1023
        const int sub = item >> 8;         // layer 4j+sub
        const int pp  = item & 255;
        {
            const int idx = (4 * j + sub) * 256 + pp;
            float s, c;
            __sincosf(clamp02pi(pe[idx]), &s, &c);
            const float a = sqrtf(1.0f - le[idx]);
            sE[sub][pp] = make_float4(c, s, a * sqrtf(0.5f + ie[idx]),
                                            a * sqrtf(0.5f - ie[idx]));
        }
        {
            float4 qv = make_float4(1.0f, 0.0f, 1.0f, 0.0f);
            if (pp < 255) {
                const int odx = (4 * j + sub) * 255 + pp;
                float s, c;
                __sincosf(clamp02pi(po[odx]), &s, &c);
                const float a = sqrtf(1.0f - lo[odx]);
                qv = make_float4(c, s, a * sqrtf(0.5f + io[odx]),
                                       a * sqrtf(0.5f - io[odx]));
            }
            sO[sub][pp] = qv;
        }
    }
    __syncthreads();

    // ---- Phase B: band-4 for steps s=0 (layers 4j,4j+1), s=1 (4j+2,4j+3) ----
#pragma unroll
    for (int s = 0; s < 2; ++s) {
        float4 h0, h1;
        compose_row(&sE[2 * s], &sO[2 * s], t, h0, h1);
        B4[s][t][0] = h0;
        B4[s][t][1] = h1;
    }
    __syncthreads();

    // ---- Phase C: band-8 product, row r = t ----
    const int r = t;
    const int base = (r & 1) ? (r - 1) : (r - 2);
    const float4 wv0 = B4[1][r][0], wv1 = B4[1][r][1];
    const float2 w0 = make_float2(wv0.x, wv0.y), w1 = make_float2(wv0.z, wv0.w);
    const float2 w2 = make_float2(wv1.x, wv1.y), w3 = make_float2(wv1.z, wv1.w);
    float2 p0 = make_float2(0.f,0.f), p1 = p0, p2 = p0, p3 = p0,
           p4 = p0, p5 = p0, p6 = p0, p7 = p0;
    {   // m=0, offset 0
        const int k = min(max(base, 0), 511);
        const float4 a = B4[0][k][0], b = B4[0][k][1];
        p0 = cfma(p0, w0, make_float2(a.x, a.y));
        p1 = cfma(p1, w0, make_float2(a.z, a.w));
        p2 = cfma(p2, w0, make_float2(b.x, b.y));
        p3 = cfma(p3, w0, make_float2(b.z, b.w));
    }
    {   // m=1, offset 2
        const int k = min(max(base + 1, 0), 511);
        const float4 a = B4[0][k][0], b = B4[0][k][1];
        p2 = cfma(p2, w1, make_float2(a.x, a.y));
        p3 = cfma(p3, w1, make_float2(a.z, a.w));
        p4 = cfma(p4, w1, make_float2(b.x, b.y));
        p5 = cfma(p5, w1, make_float2(b.z, b.w));
    }
    {   // m=2, offset 2
        const int k = min(max(base + 2, 0), 511);
        const float4 a = B4[0][k][0], b = B4[0][k][1];
        p2 = cfma(p2, w2, make_float2(a.x, a.y));
        p3 = cfma(p3, w2, make_float2(a.z, a.w));
        p4 = cfma(p4, w2, make_float2(b.x, b.y));
        p5 = cfma(p5, w2, make_float2(b.z, b.w));
    }
    {   // m=3, offset 4
        const int k = min(max(base + 3, 0), 511);
        const float4 a = B4[0][k][0], b = B4[0][k][1];
        p4 = cfma(p4, w3, make_float2(a.x, a.y));
        p5 = cfma(p5, w3, make_float2(a.z, a.w));
        p6 = cfma(p6, w3, make_float2(b.x, b.y));
        p7 = cfma(p7, w3, make_float2(b.z, b.w));
    }
    const int tp = r >> 1, hb = (r & 1) * 4;
    float4* dst = Mc8 + (size_t)j * 2048 + hb * 256 + tp;
    dst[0]   = make_float4(p0.x, p0.y, p1.x, p1.y);
    dst[256] = make_float4(p2.x, p2.y, p3.x, p3.y);
    dst[512] = make_float4(p4.x, p4.y, p5.x, p5.y);
    dst[768] = make_float4(p6.x, p6.y, p7.x, p7.y);
}

// Banded partial apply: c0 covers (a,b), c1 covers (d,e).
__device__ __forceinline__ float2 row4(const float4 c0, const float4 c1,
                                       const float2 a, const float2 b,
                                       const float2 d, const float2 e)
{
    float re = c0.x * a.x - c0.y * a.y;
    float im = c0.x * a.y + c0.y * a.x;
    re += c0.z * b.x - c0.w * b.y;  im += c0.z * b.y + c0.w * b.x;
    re += c1.x * d.x - c1.y * d.y;  im += c1.x * d.y + c1.y * d.x;
    re += c1.z * e.x - c1.w * e.y;  im += c1.z * e.y + c1.w * e.x;
    return make_float2(re, im);
}

// ---------------------------------------------------------------------------
// Kernel 2: band-8 pair-thread scan. Grid 512 x 256 (R12's proven config:
// 2 blocks/CU, 4-wave barriers). Thread t owns rows (2t, 2t+1) in registers;
// 128 supersteps, ONE barrier each (vs R12's 256). State: padded double-
// buffered LDS, S[buf][t+2] (pads 0,1,258,259 zero; they feed exactly-zero
// band coefs). Row 2t reads pairs t-2..t+1 (S[t],S[t+1],own,S[t+3]); row
// 2t+1 reads pairs t-1..t+2 (S[t+1],own,S[t+3],S[t+4]) -> 4 LDS reads +
// 1 write per superstep (R12: 6 per 2 steps). Coefs: 8 NAMED float4 regs,
// next-superstep prefetch in 8 more (R8-R10 lesson: no arrays).
// ---------------------------------------------------------------------------
__global__ __launch_bounds__(256) void mesh8_kernel(
    const float4* __restrict__ Mc8,
    const float* __restrict__ pout,
    float* __restrict__ out, const int out_size)
{
    const int t   = threadIdx.x;   // row-pair 0..255
    const int col = blockIdx.x;    // column 0..511

    __shared__ float4 S[2][260];   // [buf][pair+2] = {T.x,T.y,B.x,B.y}

    float2 T = make_float2((2 * t     == col) ? 1.0f : 0.0f, 0.0f);
    float2 B = make_float2((2 * t + 1 == col) ? 1.0f : 0.0f, 0.0f);
    S[0][t + 2] = make_float4(T.x, T.y, B.x, B.y);
    if (t < 2) {
        const float4 z = make_float4(0.f, 0.f, 0.f, 0.f);
        S[0][t] = z; S[1][t] = z;
        S[0][258 + t] = z; S[1][258 + t] = z;
    }

    float4 c0 = Mc8[t],            c1 = Mc8[256 + t],
           c2 = Mc8[512 + t],      c3 = Mc8[768 + t],
           c4 = Mc8[1024 + t],     c5 = Mc8[1280 + t],
           c6 = Mc8[1536 + t],     c7 = Mc8[1792 + t];
    __syncthreads();

#pragma unroll 1
    for (int i = 0; i < 128; ++i) {
        const int nb = ((i + 1) & 127) * 2048 + t;      // prefetch (wrap ok)
        const float4 n0 = Mc8[nb],        n1 = Mc8[nb + 256],
                     n2 = Mc8[nb + 512],  n3 = Mc8[nb + 768],
                     n4 = Mc8[nb + 1024], n5 = Mc8[nb + 1280],
                     n6 = Mc8[nb + 1536], n7 = Mc8[nb + 1792];

        const float4* SS = S[i & 1];
        const float4 s0 = SS[t], s1 = SS[t + 1], s3 = SS[t + 3], s4 = SS[t + 4];

        // row 2t: pairs t-2..t+1 (window base 2t-4)
        float2 YT = row4(c0, c1, make_float2(s0.x, s0.y), make_float2(s0.z, s0.w),
                                 make_float2(s1.x, s1.y), make_float2(s1.z, s1.w));
        YT = cadd(YT, row4(c2, c3, T, B,
                                 make_float2(s3.x, s3.y), make_float2(s3.z, s3.w)));
        // row 2t+1: pairs t-1..t+2 (window base 2t-2)
        float2 YB = row4(c4, c5, make_float2(s1.x, s1.y), make_float2(s1.z, s1.w),
                                 T, B);
        YB = cadd(YB, row4(c6, c7, make_float2(s3.x, s3.y), make_float2(s3.z, s3.w),
                                 make_float2(s4.x, s4.y), make_float2(s4.z, s4.w)));
        T = YT; B = YB;
        S[(i + 1) & 1][t + 2] = make_float4(T.x, T.y, B.x, B.y);
        __syncthreads();

        c0 = n0; c1 = n1; c2 = n2; c3 = n3;
        c4 = n4; c5 = n5; c6 = n6; c7 = n7;
    }

    // ---- output phases; expected output = Re(M), row-major, guarded ----
    float s0p, c0p, s1p, c1p;
    __sincosf(clamp02pi(pout[2 * t]),     &s0p, &c0p);
    __sincosf(clamp02pi(pout[2 * t + 1]), &s1p, &c1p);
    const int i0 = (2 * t) * 512 + col;
    const int i1 = i0 + 512;
    if (i0 < out_size) out[i0] = c0p * T.x - s0p * T.y;
    if (i1 < out_size) out[i1] = c1p * B.x - s1p * B.y;
}

// ---------------------------------------------------------------------------
// Fallback (verbatim R5 kernel, known-passing) — used only if ws too small.
// ---------------------------------------------------------------------------
__global__ __launch_bounds__(256) void mesh_kernel(
    const float* __restrict__ pe, const float* __restrict__ po,
    const float* __restrict__ pout,
    const float* __restrict__ le, const float* __restrict__ ie,
    const float* __restrict__ lo, const float* __restrict__ io,
    float* __restrict__ out, const int out_size)
{
    const int p = threadIdx.x;
    const int b = blockIdx.x;

    __shared__ float4 P[2][256];

    P[0][p] = (p == b) ? make_float4(1.0f, 0.0f, 0.0f, 0.0f)
                       : make_float4(0.0f, 0.0f, 0.0f, 0.0f);
    P[1][p] = (p == b) ? make_float4(0.0f, 0.0f, 1.0f, 0.0f)
                       : make_float4(0.0f, 0.0f, 0.0f, 0.0f);

#pragma unroll 1
    for (int i = 0; i < 256; ++i) {
        const int e0 = (2 * i) * 256 + p, e1 = e0 + 256;
        const float pe0 = pe[e0], le0 = le[e0], ie0 = ie[e0];
        const float pe1 = pe[e1], le1 = le[e1], ie1 = ie[e1];
        float po0 = 0.0f, lo0 = 0.0f, io0 = 0.0f;
        float po1 = 0.0f, lo1 = 0.0f, io1 = 0.0f;
        if (p < 255) {
            const int o0 = (2 * i) * 255 + p, o1 = o0 + 255;
            po0 = po[o0]; lo0 = lo[o0]; io0 = io[o0];
            po1 = po[o1]; lo1 = lo[o1]; io1 = io[o1];
        }

        float4 v0 = P[0][p];
        float4 v1 = P[1][p];
#pragma unroll
        for (int j = 0; j < 2; ++j) {
            float s, c;
            __sincosf(clamp02pi(j ? pe1 : pe0), &s, &c);
            const float a  = sqrtf(1.0f - (j ? le1 : le0));
            const float tt = a * sqrtf(0.5f + (j ? ie1 : ie0));
            const float rr = a * sqrtf(0.5f - (j ? ie1 : ie0));
            {
                const float ptr_ = c * v0.x - s * v0.y;
                const float pti_ = c * v0.y + s * v0.x;
                v0 = make_float4(tt * ptr_ - rr * v0.w, tt * pti_ + rr * v0.z,
                                 tt * v0.z - rr * pti_, tt * v0.w + rr * ptr_);
            }
            {
                const float ptr_ = c * v1.x - s * v1.y;
                const float pti_ = c * v1.y + s * v1.x;
                v1 = make_float4(tt * ptr_ - rr * v1.w, tt * pti_ + rr * v1.z,
                                 tt * v1.z - rr * pti_, tt * v1.w + rr * ptr_);
            }
        }
        P[0][p] = v0;
        P[1][p] = v1;
        __syncthreads();

        if (p < 255) {
            float2 top0 = make_float2(P[0][p].z, P[0][p].w);
            float2 bot0 = make_float2(P[0][p + 1].x, P[0][p + 1].y);
            float2 top1 = make_float2(P[1][p].z, P[1][p].w);
            float2 bot1 = make_float2(P[1][p + 1].x, P[1][p + 1].y);
#pragma unroll
            for (int j = 0; j < 2; ++j) {
                float s, c;
                __sincosf(clamp02pi(j ? po1 : po0), &s, &c);
                const float a  = sqrtf(1.0f - (j ? lo1 : lo0));
                const float tt = a * sqrtf(0.5f + (j ? io1 : io0));
                const float rr = a * sqrtf(0.5f - (j ? io1 : io0));
                {
                    const float ptr_ = c * top0.x - s * top0.y;
                    const float pti_ = c * top0.y + s * top0.x;
                    const float nbx = tt * bot0.x - rr * pti_;
                    const float nby = tt * bot0.y + rr * ptr_;
                    top0 = make_float2(tt * ptr_ - rr * bot0.y, tt * pti_ + rr * bot0.x);
                    bot0 = make_float2(nbx, nby);
                }
                {
                    const float ptr_ = c * top1.x - s * top1.y;
                    const float pti_ = c * top1.y + s * top1.x;
                    const float nbx = tt * bot1.x - rr * pti_;
                    const float nby = tt * bot1.y + rr * ptr_;
                    top1 = make_float2(tt * ptr_ - rr * bot1.y, tt * pti_ + rr * bot1.x);
                    bot1 = make_float2(nbx, nby);
                }
            }
            P[0][p].z = top0.x; P[0][p].w = top0.y;
            P[0][p + 1].x = bot0.x; P[0][p + 1].y = bot0.y;
            P[1][p].z = top1.x; P[1][p].w = top1.y;
            P[1][p + 1].x = bot1.x; P[1][p + 1].y = bot1.y;
        }
        __syncthreads();
    }

    const float4 v0 = P[0][p];
    const float4 v1 = P[1][p];
    float s0, c0, s1, c1;
    __sincosf(clamp02pi(pout[2 * p]),     &s0, &c0);
    __sincosf(clamp02pi(pout[2 * p + 1]), &s1, &c1);

    float4 w0, w1;
    w0.x = c0 * v0.x - s0 * v0.y;  w0.y = c0 * v0.y + s0 * v0.x;
    w0.z = c0 * v1.x - s0 * v1.y;  w0.w = c0 * v1.y + s0 * v1.x;
    w1.x = c1 * v0.z - s1 * v0.w;  w1.y = c1 * v0.w + s1 * v0.z;
    w1.z = c1 * v1.z - s1 * v1.w;  w1.w = c1 * v1.w + s1 * v1.z;

    const int i0 = (2 * p) * 512 + 2 * b;
    const int i1 = (2 * p + 1) * 512 + 2 * b;
    if (i0 + 1 < out_size) *(float2*)(out + i0) = make_float2(w0.x, w0.z);
    if (i1 + 1 < out_size) *(float2*)(out + i1) = make_float2(w1.x, w1.z);
}

extern "C" void kernel_launch(void* const* d_in, const int* in_sizes, int n_in,
                              void* d_out, int out_size, void* d_ws, size_t ws_size,
                              hipStream_t stream)
{
    const float* pe   = (const float*)d_in[0];  // pc_even_phases  [512][256]
    const float* po   = (const float*)d_in[1];  // pc_odd_phases   [512][255]
    const float* pout = (const float*)d_in[2];  // pc_out_phases   [512]
    const float* le   = (const float*)d_in[3];  // mmi_loss_even   [512][256]
    const float* ie   = (const float*)d_in[4];  // mmi_imb_even    [512][256]
    const float* lo   = (const float*)d_in[5];  // mmi_loss_odd    [512][255]
    const float* io   = (const float*)d_in[6];  // mmi_imb_odd     [512][255]

    const size_t need = (size_t)128 * 2048 * sizeof(float4);  // 4 MB
    if (ws_size >= need) {
        float4* Mc8 = (float4*)d_ws;
        compose8_kernel<<<128, 512, 0, stream>>>(pe, po, le, ie, lo, io, Mc8);
        mesh8_kernel<<<512, 256, 0, stream>>>(Mc8, pout, (float*)d_out, out_size);
    } else {
        mesh_kernel<<<256, 256, 0, stream>>>(pe, po, pout, le, ie, lo, io,
                                             (float*)d_out, out_size);
    }
}

// Round 16
// 144.804 us; speedup vs baseline: 2.2053x; 1.0378x over previous
//
#include <hip/hip_runtime.h>
#include <hip/hip_fp16.h>

#define TWO_PI_F 6.283185307179586f

__device__ __forceinline__ float clamp02pi(float x) {
    return fminf(fmaxf(x, 0.0f), TWO_PI_F);
}

__device__ __forceinline__ float2 cmul(const float2 a, const float2 b) {
    return make_float2(a.x * b.x - a.y * b.y, a.x * b.y + a.y * b.x);
}
__device__ __forceinline__ float2 cadd(const float2 a, const float2 b) {
    return make_float2(a.x + b.x, a.y + b.y);
}
__device__ __forceinline__ float2 cscale(const float s, const float2 a) {
    return make_float2(s * a.x, s * a.y);
}
__device__ __forceinline__ float2 imul(const float r, const float2 e) {  // i*r*e
    return make_float2(-r * e.y, r * e.x);
}
__device__ __forceinline__ float2 cfma(const float2 acc, const float2 a, const float2 b) {
    return make_float2(acc.x + a.x * b.x - a.y * b.y,
                       acc.y + a.x * b.y + a.y * b.x);
}

// half2 <-> float2 via bit_cast (register-only, no memory reinterpret).
__device__ __forceinline__ float2 h2f(const unsigned u) {
    return __half22float2(__builtin_bit_cast(__half2, u));
}
__device__ __forceinline__ unsigned f2h(const float2 f) {
    return __builtin_bit_cast(unsigned, __float22half2_rn(f));
}

// Band-4 composition of row r for one 4-layer step (math verbatim R12-R15 —
// verified, absmax 3.7e-9). h0 = cols base..base+1, h1 = cols base+2..base+3,
// base = r even ? r-2 : r-1. Row 0: h0 = 0. Row 511: h1 = 0.
__device__ __forceinline__ void compose_row(
    const float4 (*sE)[256], const float4 (*sO)[256], const int r,
    float4& h0, float4& h1)
{
    float2 f0, f1, f2, f3;
    if (r == 0) {
        const float4 q1 = sE[1][0], q0 = sE[0][0];
        const float2 e1 = make_float2(q1.x, q1.y);
        const float2 e0 = make_float2(q0.x, q0.y);
        const float2 v2 = cscale(q1.z, e1);
        const float2 v3 = make_float2(0.0f, q1.w);
        f2 = cadd(cmul(v2, cscale(q0.z, e0)), cmul(v3, imul(q0.w, e0)));
        f3 = cadd(cmul(v2, make_float2(0.0f, q0.w)), cscale(q0.z, v3));
        f0 = make_float2(0.0f, 0.0f);
        f1 = make_float2(0.0f, 0.0f);
    } else {
        const int pidx = (r - 1) >> 1;
        const int qidx = min(pidx + 1, 255);      // r=511: u2==0, value unused
        const float4 qO1 = sO[1][pidx], qO0 = sO[0][pidx];
        const float2 eO1 = make_float2(qO1.x, qO1.y);
        const float2 eO0 = make_float2(qO0.x, qO0.y);
        float2 w1, w2;
        if (r & 1) { w1 = cscale(qO1.z, eO1); w2 = make_float2(0.0f, qO1.w); }
        else       { w1 = imul(qO1.w, eO1);   w2 = make_float2(qO1.z, 0.0f); }
        const float2 u1 = cadd(cmul(w1, cscale(qO0.z, eO0)),
                               cmul(w2, imul(qO0.w, eO0)));
        const float2 u2 = cadd(cmul(w1, make_float2(0.0f, qO0.w)),
                               cscale(qO0.z, w2));
        const float4 qE1p = sE[1][pidx], qE1q = sE[1][qidx];
        const float4 qE0p = sE[0][pidx], qE0q = sE[0][qidx];
        const float2 eE1p = make_float2(qE1p.x, qE1p.y);
        const float2 eE1q = make_float2(qE1q.x, qE1q.y);
        const float2 eE0p = make_float2(qE0p.x, qE0p.y);
        const float2 eE0q = make_float2(qE0q.x, qE0q.y);
        const float2 v0 = cmul(u1, imul(qE1p.w, eE1p));
        const float2 v1 = cscale(qE1p.z, u1);
        const float2 v2 = cmul(u2, cscale(qE1q.z, eE1q));
        const float2 v3 = cmul(u2, make_float2(0.0f, qE1q.w));
        f0 = cadd(cmul(v0, cscale(qE0p.z, eE0p)), cmul(v1, imul(qE0p.w, eE0p)));
        f1 = cadd(cmul(v0, make_float2(0.0f, qE0p.w)), cscale(qE0p.z, v1));
        f2 = cadd(cmul(v2, cscale(qE0q.z, eE0q)), cmul(v3, imul(qE0q.w, eE0q)));
        f3 = cadd(cmul(v2, make_float2(0.0f, qE0q.w)), cscale(qE0q.z, v3));
    }
    h0 = make_float4(f0.x, f0.y, f1.x, f1.y);
    h1 = make_float4(f2.x, f2.y, f3.x, f3.y);
}

// ---------------------------------------------------------------------------
// Kernel 1: fused 2-level composition -> FP16 band-8 operator (structure
// verbatim R15 — verified; only the output pack changed to half precision).
// Output: Mch[j*1024 + h*256 + (r>>1)] (uint4 = 8 halves = 4 complex):
//   h = (r&1)*2 + 0: row r band cols 0..3; +1: band cols 4..7.
// Row 2t window base 2t-4; row 2t+1 window base 2t-2. Out-of-window entries
// are EXACT zeros (fp16 preserves 0) -> mesh pad trick stays valid.
// ---------------------------------------------------------------------------
__global__ __launch_bounds__(512) void compose8_kernel(
    const float* __restrict__ pe, const float* __restrict__ po,
    const float* __restrict__ le, const float* __restrict__ ie,
    const float* __restrict__ lo, const float* __restrict__ io,
    uint4* __restrict__ Mch)
{
    const int j = blockIdx.x;    // superstep 0..127
    const int t = threadIdx.x;   // 0..511

    __shared__ float4 sE[4][256];      // 16 KB
    __shared__ float4 sO[4][256];      // 16 KB
    __shared__ float4 B4[2][512][2];   // 32 KB: [step][row][h]

    // ---- Phase A: stage layer coefs (each thread: 2 E + 2 O) ----
#pragma unroll
    for (int q = 0; q < 2; ++q) {
        const int item = q * 512 + t;
        const int sub = item >> 8;
        const int pp  = item & 255;
        {
            const int idx = (4 * j + sub) * 256 + pp;
            float s, c;
            __sincosf(clamp02pi(pe[idx]), &s, &c);
            const float a = sqrtf(1.0f - le[idx]);
            sE[sub][pp] = make_float4(c, s, a * sqrtf(0.5f + ie[idx]),
                                            a * sqrtf(0.5f - ie[idx]));
        }
        {
            float4 qv = make_float4(1.0f, 0.0f, 1.0f, 0.0f);
            if (pp < 255) {
                const int odx = (4 * j + sub) * 255 + pp;
                float s, c;
                __sincosf(clamp02pi(po[odx]), &s, &c);
                const float a = sqrtf(1.0f - lo[odx]);
                qv = make_float4(c, s, a * sqrtf(0.5f + io[odx]),
                                       a * sqrtf(0.5f - io[odx]));
            }
            sO[sub][pp] = qv;
        }
    }
    __syncthreads();

    // ---- Phase B: band-4 for child steps s=0,1 ----
#pragma unroll
    for (int s = 0; s < 2; ++s) {
        float4 h0, h1;
        compose_row(&sE[2 * s], &sO[2 * s], t, h0, h1);
        B4[s][t][0] = h0;
        B4[s][t][1] = h1;
    }
    __syncthreads();

    // ---- Phase C: band-8 product P = S2*S1, row r = t (verbatim R15) ----
    const int r = t;
    const int base = (r & 1) ? (r - 1) : (r - 2);
    const float4 wv0 = B4[1][r][0], wv1 = B4[1][r][1];
    const float2 w0 = make_float2(wv0.x, wv0.y), w1 = make_float2(wv0.z, wv0.w);
    const float2 w2 = make_float2(wv1.x, wv1.y), w3 = make_float2(wv1.z, wv1.w);
    float2 p0 = make_float2(0.f,0.f), p1 = p0, p2 = p0, p3 = p0,
           p4 = p0, p5 = p0, p6 = p0, p7 = p0;
    {   // m=0, offset 0
        const int k = min(max(base, 0), 511);
        const float4 a = B4[0][k][0], b = B4[0][k][1];
        p0 = cfma(p0, w0, make_float2(a.x, a.y));
        p1 = cfma(p1, w0, make_float2(a.z, a.w));
        p2 = cfma(p2, w0, make_float2(b.x, b.y));
        p3 = cfma(p3, w0, make_float2(b.z, b.w));
    }
    {   // m=1, offset 2
        const int k = min(max(base + 1, 0), 511);
        const float4 a = B4[0][k][0], b = B4[0][k][1];
        p2 = cfma(p2, w1, make_float2(a.x, a.y));
        p3 = cfma(p3, w1, make_float2(a.z, a.w));
        p4 = cfma(p4, w1, make_float2(b.x, b.y));
        p5 = cfma(p5, w1, make_float2(b.z, b.w));
    }
    {   // m=2, offset 2
        const int k = min(max(base + 2, 0), 511);
        const float4 a = B4[0][k][0], b = B4[0][k][1];
        p2 = cfma(p2, w2, make_float2(a.x, a.y));
        p3 = cfma(p3, w2, make_float2(a.z, a.w));
        p4 = cfma(p4, w2, make_float2(b.x, b.y));
        p5 = cfma(p5, w2, make_float2(b.z, b.w));
    }
    {   // m=3, offset 4
        const int k = min(max(base + 3, 0), 511);
        const float4 a = B4[0][k][0], b = B4[0][k][1];
        p4 = cfma(p4, w3, make_float2(a.x, a.y));
        p5 = cfma(p5, w3, make_float2(a.z, a.w));
        p6 = cfma(p6, w3, make_float2(b.x, b.y));
        p7 = cfma(p7, w3, make_float2(b.z, b.w));
    }
    const int hb = (r & 1) * 2;
    uint4* dst = Mch + (size_t)j * 1024 + hb * 256 + (r >> 1);
    dst[0]   = make_uint4(f2h(p0), f2h(p1), f2h(p2), f2h(p3));
    dst[256] = make_uint4(f2h(p4), f2h(p5), f2h(p6), f2h(p7));
}

// fp16 band-8 partial apply: q packs 4 complex coefs over inputs (a,b,d,e).
__device__ __forceinline__ float2 hrow4(const uint4 q, const float2 a,
                                        const float2 b, const float2 d,
                                        const float2 e, float2 acc)
{
    acc = cfma(acc, h2f(q.x), a);
    acc = cfma(acc, h2f(q.y), b);
    acc = cfma(acc, h2f(q.z), d);
    acc = cfma(acc, h2f(q.w), e);
    return acc;
}

// ---------------------------------------------------------------------------
// Kernel 2: band-8 pair-thread scan with FP16 coefs (structure verbatim R15:
// grid 512 x 256, 2 blocks/CU, ONE barrier per superstep, padded double-
// buffered fp32 LDS state). Coef loads halve to 64 B/thread/superstep
// (4 x uint4, coalesced) — the measured co-dominant L2 term.
// ---------------------------------------------------------------------------
__global__ __launch_bounds__(256) void mesh8h_kernel(
    const uint4* __restrict__ Mch,
    const float* __restrict__ pout,
    float* __restrict__ out, const int out_size)
{
    const int t   = threadIdx.x;   // row-pair 0..255
    const int col = blockIdx.x;    // column 0..511

    __shared__ float4 S[2][260];   // [buf][pair+2] = {T.x,T.y,B.x,B.y}

    float2 T = make_float2((2 * t     == col) ? 1.0f : 0.0f, 0.0f);
    float2 B = make_float2((2 * t + 1 == col) ? 1.0f : 0.0f, 0.0f);
    S[0][t + 2] = make_float4(T.x, T.y, B.x, B.y);
    if (t < 2) {
        const float4 z = make_float4(0.f, 0.f, 0.f, 0.f);
        S[0][t] = z; S[1][t] = z;
        S[0][258 + t] = z; S[1][258 + t] = z;
    }

    uint4 c0 = Mch[t],       c1 = Mch[256 + t],
          c2 = Mch[512 + t], c3 = Mch[768 + t];
    __syncthreads();

#pragma unroll 1
    for (int i = 0; i < 128; ++i) {
        const int nb = ((i + 1) & 127) * 1024 + t;      // prefetch (wrap ok)
        const uint4 n0 = Mch[nb],       n1 = Mch[nb + 256],
                    n2 = Mch[nb + 512], n3 = Mch[nb + 768];

        const float4* SS = S[i & 1];
        const float4 s0 = SS[t], s1 = SS[t + 1], s3 = SS[t + 3], s4 = SS[t + 4];

        // row 2t: pairs t-2..t+1 (window base 2t-4)
        float2 YT = hrow4(c0, make_float2(s0.x, s0.y), make_float2(s0.z, s0.w),
                              make_float2(s1.x, s1.y), make_float2(s1.z, s1.w),
                          make_float2(0.f, 0.f));
        YT = hrow4(c1, T, B,
                       make_float2(s3.x, s3.y), make_float2(s3.z, s3.w), YT);
        // row 2t+1: pairs t-1..t+2 (window base 2t-2)
        float2 YB = hrow4(c2, make_float2(s1.x, s1.y), make_float2(s1.z, s1.w),
                              T, B, make_float2(0.f, 0.f));
        YB = hrow4(c3, make_float2(s3.x, s3.y), make_float2(s3.z, s3.w),
                       make_float2(s4.x, s4.y), make_float2(s4.z, s4.w), YB);
        T = YT; B = YB;
        S[(i + 1) & 1][t + 2] = make_float4(T.x, T.y, B.x, B.y);
        __syncthreads();

        c0 = n0; c1 = n1; c2 = n2; c3 = n3;
    }

    // ---- output phases; expected output = Re(M), row-major, guarded ----
    float s0p, c0p, s1p, c1p;
    __sincosf(clamp02pi(pout[2 * t]),     &s0p, &c0p);
    __sincosf(clamp02pi(pout[2 * t + 1]), &s1p, &c1p);
    const int i0 = (2 * t) * 512 + col;
    const int i1 = i0 + 512;
    if (i0 < out_size) out[i0] = c0p * T.x - s0p * T.y;
    if (i1 < out_size) out[i1] = c1p * B.x - s1p * B.y;
}

// ---------------------------------------------------------------------------
// Fallback (verbatim R5 kernel, known-passing) — used only if ws too small.
// ---------------------------------------------------------------------------
__global__ __launch_bounds__(256) void mesh_kernel(
    const float* __restrict__ pe, const float* __restrict__ po,
    const float* __restrict__ pout,
    const float* __restrict__ le, const float* __restrict__ ie,
    const float* __restrict__ lo, const float* __restrict__ io,
    float* __restrict__ out, const int out_size)
{
    const int p = threadIdx.x;
    const int b = blockIdx.x;

    __shared__ float4 P[2][256];

    P[0][p] = (p == b) ? make_float4(1.0f, 0.0f, 0.0f, 0.0f)
                       : make_float4(0.0f, 0.0f, 0.0f, 0.0f);
    P[1][p] = (p == b) ? make_float4(0.0f, 0.0f, 1.0f, 0.0f)
                       : make_float4(0.0f, 0.0f, 0.0f, 0.0f);

#pragma unroll 1
    for (int i = 0; i < 256; ++i) {
        const int e0 = (2 * i) * 256 + p, e1 = e0 + 256;
        const float pe0 = pe[e0], le0 = le[e0], ie0 = ie[e0];
        const float pe1 = pe[e1], le1 = le[e1], ie1 = ie[e1];
        float po0 = 0.0f, lo0 = 0.0f, io0 = 0.0f;
        float po1 = 0.0f, lo1 = 0.0f, io1 = 0.0f;
        if (p < 255) {
            const int o0 = (2 * i) * 255 + p, o1 = o0 + 255;
            po0 = po[o0]; lo0 = lo[o0]; io0 = io[o0];
            po1 = po[o1]; lo1 = lo[o1]; io1 = io[o1];
        }

        float4 v0 = P[0][p];
        float4 v1 = P[1][p];
#pragma unroll
        for (int j = 0; j < 2; ++j) {
            float s, c;
            __sincosf(clamp02pi(j ? pe1 : pe0), &s, &c);
            const float a  = sqrtf(1.0f - (j ? le1 : le0));
            const float tt = a * sqrtf(0.5f + (j ? ie1 : ie0));
            const float rr = a * sqrtf(0.5f - (j ? ie1 : ie0));
            {
                const float ptr_ = c * v0.x - s * v0.y;
                const float pti_ = c * v0.y + s * v0.x;
                v0 = make_float4(tt * ptr_ - rr * v0.w, tt * pti_ + rr * v0.z,
                                 tt * v0.z - rr * pti_, tt * v0.w + rr * ptr_);
            }
            {
                const float ptr_ = c * v1.x - s * v1.y;
                const float pti_ = c * v1.y + s * v1.x;
                v1 = make_float4(tt * ptr_ - rr * v1.w, tt * pti_ + rr * v1.z,
                                 tt * v1.z - rr * pti_, tt * v1.w + rr * ptr_);
            }
        }
        P[0][p] = v0;
        P[1][p] = v1;
        __syncthreads();

        if (p < 255) {
            float2 top0 = make_float2(P[0][p].z, P[0][p].w);
            float2 bot0 = make_float2(P[0][p + 1].x, P[0][p + 1].y);
            float2 top1 = make_float2(P[1][p].z, P[1][p].w);
            float2 bot1 = make_float2(P[1][p + 1].x, P[1][p + 1].y);
#pragma unroll
            for (int j = 0; j < 2; ++j) {
                float s, c;
                __sincosf(clamp02pi(j ? po1 : po0), &s, &c);
                const float a  = sqrtf(1.0f - (j ? lo1 : lo0));
                const float tt = a * sqrtf(0.5f + (j ? io1 : io0));
                const float rr = a * sqrtf(0.5f - (j ? io1 : io0));
                {
                    const float ptr_ = c * top0.x - s * top0.y;
                    const float pti_ = c * top0.y + s * top0.x;
                    const float nbx = tt * bot0.x - rr * pti_;
                    const float nby = tt * bot0.y + rr * ptr_;
                    top0 = make_float2(tt * ptr_ - rr * bot0.y, tt * pti_ + rr * bot0.x);
                    bot0 = make_float2(nbx, nby);
                }
                {
                    const float ptr_ = c * top1.x - s * top1.y;
                    const float pti_ = c * top1.y + s * top1.x;
                    const float nbx = tt * bot1.x - rr * pti_;
                    const float nby = tt * bot1.y + rr * ptr_;
                    top1 = make_float2(tt * ptr_ - rr * bot1.y, tt * pti_ + rr * bot1.x);
                    bot1 = make_float2(nbx, nby);
                }
            }
            P[0][p].z = top0.x; P[0][p].w = top0.y;
            P[0][p + 1].x = bot0.x; P[0][p + 1].y = bot0.y;
            P[1][p].z = top1.x; P[1][p].w = top1.y;
            P[1][p + 1].x = bot1.x; P[1][p + 1].y = bot1.y;
        }
        __syncthreads();
    }

    const float4 v0 = P[0][p];
    const float4 v1 = P[1][p];
    float s0, c0, s1, c1;
    __sincosf(clamp02pi(pout[2 * p]),     &s0, &c0);
    __sincosf(clamp02pi(pout[2 * p + 1]), &s1, &c1);

    float4 w0, w1;
    w0.x = c0 * v0.x - s0 * v0.y;  w0.y = c0 * v0.y + s0 * v0.x;
    w0.z = c0 * v1.x - s0 * v1.y;  w0.w = c0 * v1.y + s0 * v1.x;
    w1.x = c1 * v0.z - s1 * v0.w;  w1.y = c1 * v0.w + s1 * v0.z;
    w1.z = c1 * v1.z - s1 * v1.w;  w1.w = c1 * v1.w + s1 * v1.z;

    const int i0 = (2 * p) * 512 + 2 * b;
    const int i1 = (2 * p + 1) * 512 + 2 * b;
    if (i0 + 1 < out_size) *(float2*)(out + i0) = make_float2(w0.x, w0.z);
    if (i1 + 1 < out_size) *(float2*)(out + i1) = make_float2(w1.x, w1.z);
}

extern "C" void kernel_launch(void* const* d_in, const int* in_sizes, int n_in,
                              void* d_out, int out_size, void* d_ws, size_t ws_size,
                              hipStream_t stream)
{
    const float* pe   = (const float*)d_in[0];  // pc_even_phases  [512][256]
    const float* po   = (const float*)d_in[1];  // pc_odd_phases   [512][255]
    const float* pout = (const float*)d_in[2];  // pc_out_phases   [512]
    const float* le   = (const float*)d_in[3];  // mmi_loss_even   [512][256]
    const float* ie   = (const float*)d_in[4];  // mmi_imb_even    [512][256]
    const float* lo   = (const float*)d_in[5];  // mmi_loss_odd    [512][255]
    const float* io   = (const float*)d_in[6];  // mmi_imb_odd     [512][255]

    const size_t need = (size_t)128 * 1024 * sizeof(uint4);  // 2 MB
    if (ws_size >= need) {
        uint4* Mch = (uint4*)d_ws;
        compose8_kernel<<<128, 512, 0, stream>>>(pe, po, le, ie, lo, io, Mch);
        mesh8h_kernel<<<512, 256, 0, stream>>>(Mch, pout, (float*)d_out, out_size);
    } else {
        mesh_kernel<<<256, 256, 0, stream>>>(pe, po, pout, le, ie, lo, io,
                                             (float*)d_out, out_size);
    }
}